// Round 1
// baseline (1212.301 us; speedup 1.0000x reference)
//
#include <hip/hip_runtime.h>
#include <math.h>

// Physics_Attention: B=1, N=65536, DIM=256, H=8, D=64, G=64
#define NPTS  65536
#define DIMX  256
#define NH    8
#define HDIM  512   // H*D
// ws layout (floats):
//   xmid  [NPTS][512]            = 33.55M
//   sw    [NPTS][512] (h*64+g)   = 33.55M
//   stp   [H][64ch][64g][64c]    = 2.10M   (slice_token partials per chunk)
//   normp [H][64ch][64g]         = 32768
//   Mt    [256][512]             = 131072  (folded out_slice @ Wout^T)
// total ~278 MB

__device__ __forceinline__ float gelu_f(float x) {
    return 0.5f * x * (1.0f + erff(x * 0.7071067811865476f));
}

// ---------------------------------------------------------------------------
// C[m][o] = sum_k A[m][k]*B[o][k] + bias[o]; 128x128 tile, 8x8/thread, KC=8
// ---------------------------------------------------------------------------
template<int K>
__global__ __launch_bounds__(256)
void gemm_f32(const float* __restrict__ A, const float* __restrict__ B,
              const float* __restrict__ bias, float* __restrict__ C, int O) {
    __shared__ float As[8][132];
    __shared__ float Bs[8][132];
    const int m0 = blockIdx.x * 128;
    const int o0 = blockIdx.y * 128;
    const int t  = threadIdx.x;
    const int tx = t & 15, ty = t >> 4;
    const int r  = t >> 1, c4 = (t & 1) * 4;
    float acc[8][8];
    #pragma unroll
    for (int i = 0; i < 8; ++i)
        #pragma unroll
        for (int j = 0; j < 8; ++j) acc[i][j] = 0.f;

    const float* Ap = A + (size_t)(m0 + r) * K + c4;
    const float* Bp = B + (size_t)(o0 + r) * K + c4;

    for (int kc = 0; kc < K; kc += 8) {
        float4 av = *(const float4*)(Ap + kc);
        float4 bv = *(const float4*)(Bp + kc);
        __syncthreads();
        As[c4+0][r] = av.x; As[c4+1][r] = av.y; As[c4+2][r] = av.z; As[c4+3][r] = av.w;
        Bs[c4+0][r] = bv.x; Bs[c4+1][r] = bv.y; Bs[c4+2][r] = bv.z; Bs[c4+3][r] = bv.w;
        __syncthreads();
        #pragma unroll
        for (int kk = 0; kk < 8; ++kk) {
            float a_[8], b_[8];
            #pragma unroll
            for (int i = 0; i < 8; ++i) a_[i] = As[kk][ty*8 + i];
            #pragma unroll
            for (int j = 0; j < 8; ++j) b_[j] = Bs[kk][tx*8 + j];
            #pragma unroll
            for (int i = 0; i < 8; ++i)
                #pragma unroll
                for (int j = 0; j < 8; ++j)
                    acc[i][j] = fmaf(a_[i], b_[j], acc[i][j]);
        }
    }
    float bb[8];
    #pragma unroll
    for (int j = 0; j < 8; ++j) bb[j] = bias[o0 + tx*8 + j];
    #pragma unroll
    for (int i = 0; i < 8; ++i) {
        float* cp = C + (size_t)(m0 + ty*8 + i) * O + o0 + tx*8;
        float4 v0 = make_float4(acc[i][0]+bb[0], acc[i][1]+bb[1], acc[i][2]+bb[2], acc[i][3]+bb[3]);
        float4 v1 = make_float4(acc[i][4]+bb[4], acc[i][5]+bb[5], acc[i][6]+bb[6], acc[i][7]+bb[7]);
        *(float4*)cp       = v0;
        *(float4*)(cp + 4) = v1;
    }
}

// ---------------------------------------------------------------------------
// Per (n,h): temp MLP + logits + gumbel softmax -> sw[n][h][g]
// One wave per point; Ws/Wt1 rows live in registers (lane g owns row g).
// ---------------------------------------------------------------------------
__global__ __launch_bounds__(256)
void slice_weights_kernel(const float* __restrict__ xmid,
                          const float* __restrict__ Wt1, const float* __restrict__ bt1,
                          const float* __restrict__ Wt2, const float* __restrict__ bt2,
                          const float* __restrict__ biasp,
                          const float* __restrict__ Ws,  const float* __restrict__ bs,
                          const float* __restrict__ u,
                          float* __restrict__ sw) {
    __shared__ float xv[4][64];
    const int lane = threadIdx.x & 63;
    const int wv   = threadIdx.x >> 6;
    const int waveId = blockIdx.x * 4 + wv;
    const int nWaves = gridDim.x * 4;

    float wsr[64], wt1r[64];
    #pragma unroll
    for (int k4 = 0; k4 < 16; ++k4) {
        float4 a = *(const float4*)&Ws [lane*64 + k4*4];
        float4 b = *(const float4*)&Wt1[lane*64 + k4*4];
        wsr [k4*4+0] = a.x; wsr [k4*4+1] = a.y; wsr [k4*4+2] = a.z; wsr [k4*4+3] = a.w;
        wt1r[k4*4+0] = b.x; wt1r[k4*4+1] = b.y; wt1r[k4*4+2] = b.z; wt1r[k4*4+3] = b.w;
    }
    const float wt2r = Wt2[lane];
    const float bsv  = bs[lane];
    const float bt1v = bt1[lane];
    const float bt2v = bt2[0];

    for (int n = waveId; n < NPTS; n += nWaves) {
        #pragma unroll 1
        for (int h = 0; h < NH; ++h) {
            xv[wv][lane] = xmid[(size_t)n * HDIM + h*64 + lane];
            __syncthreads();
            float l0 = bsv, l1 = 0.f, t0 = bt1v, t1 = 0.f;
            const float4* xv4 = (const float4*)xv[wv];
            #pragma unroll
            for (int k4 = 0; k4 < 16; ++k4) {
                float4 xk = xv4[k4];
                l0 = fmaf(xk.x, wsr [k4*4+0], l0);
                l1 = fmaf(xk.y, wsr [k4*4+1], l1);
                l0 = fmaf(xk.z, wsr [k4*4+2], l0);
                l1 = fmaf(xk.w, wsr [k4*4+3], l1);
                t0 = fmaf(xk.x, wt1r[k4*4+0], t0);
                t1 = fmaf(xk.y, wt1r[k4*4+1], t1);
                t0 = fmaf(xk.z, wt1r[k4*4+2], t0);
                t1 = fmaf(xk.w, wt1r[k4*4+3], t1);
            }
            float logit = l0 + l1;
            float t1v   = t0 + t1;
            // temp = gelu(gelu(t1) @ Wt2^T + bt2) + bias[h], clamp 0.01
            float term = gelu_f(t1v) * wt2r;
            #pragma unroll
            for (int off = 32; off; off >>= 1) term += __shfl_xor(term, off);
            float temp = gelu_f(term + bt2v) + biasp[h];
            temp = fmaxf(temp, 0.01f);
            // gumbel softmax over g (=lane)
            float uu = u[((size_t)h * NPTS + n) * 64 + lane];
            float gn = -logf(-logf(uu + 1e-8f) + 1e-8f);
            float s  = (logit + gn) / temp;
            float m = s;
            #pragma unroll
            for (int off = 32; off; off >>= 1) m = fmaxf(m, __shfl_xor(m, off));
            float p = expf(s - m);
            float ps = p;
            #pragma unroll
            for (int off = 32; off; off >>= 1) ps += __shfl_xor(ps, off);
            sw[((size_t)n * NH + h) * 64 + lane] = p / ps;
        }
    }
}

// ---------------------------------------------------------------------------
// Per (h, chunk of 1024 pts): partial slice_tokens[g][c] and norm[g]
// thread (q=t>>6, c=t&63) owns g in [q*16, q*16+16) x column c
// ---------------------------------------------------------------------------
__global__ __launch_bounds__(256)
void gather_kernel(const float* __restrict__ xmid, const float* __restrict__ sw,
                   float* __restrict__ stp, float* __restrict__ normp) {
    __shared__ float xt [64][68];
    __shared__ float stl[64][68];
    __shared__ float nacc[4][64];
    const int h  = blockIdx.y;
    const int n0 = blockIdx.x * 1024;
    const int t  = threadIdx.x;
    const int q  = t >> 6, c = t & 63;
    float acc[16];
    #pragma unroll
    for (int i = 0; i < 16; ++i) acc[i] = 0.f;
    float nsum = 0.f;

    for (int tile = 0; tile < 16; ++tile) {
        const int pt = n0 + tile * 64;
        __syncthreads();
        #pragma unroll
        for (int i = 0; i < 4; ++i) {
            int idx = t + i * 256;
            int p = idx >> 4, cc = (idx & 15) * 4;
            *(float4*)&xt [p][cc] = *(const float4*)&xmid[(size_t)(pt + p) * HDIM + h*64 + cc];
            *(float4*)&stl[p][cc] = *(const float4*)&sw [((size_t)(pt + p) * NH + h) * 64 + cc];
        }
        __syncthreads();
        for (int p = 0; p < 64; ++p) {
            float xvv = xt[p][c];
            #pragma unroll
            for (int i4 = 0; i4 < 4; ++i4) {
                float4 sv = *(const float4*)&stl[p][q*16 + i4*4];
                acc[i4*4+0] = fmaf(sv.x, xvv, acc[i4*4+0]);
                acc[i4*4+1] = fmaf(sv.y, xvv, acc[i4*4+1]);
                acc[i4*4+2] = fmaf(sv.z, xvv, acc[i4*4+2]);
                acc[i4*4+3] = fmaf(sv.w, xvv, acc[i4*4+3]);
            }
        }
        #pragma unroll
        for (int pp = 0; pp < 16; ++pp) nsum += stl[q*16 + pp][c];
    }
    const size_t pbase = ((size_t)h * 64 + blockIdx.x) * 4096;
    #pragma unroll
    for (int i = 0; i < 16; ++i)
        stp[pbase + (size_t)(q*16 + i)*64 + c] = acc[i];
    nacc[q][c] = nsum;
    __syncthreads();
    if (t < 64)
        normp[((size_t)h * 64 + blockIdx.x) * 64 + t] =
            nacc[0][t] + nacc[1][t] + nacc[2][t] + nacc[3][t];
}

// ---------------------------------------------------------------------------
// Per head: reduce partials, normalize, qkv, 64x64 attention, and fold
// out_slice into Wout: Mt[i][h*64+g] = sum_d os[g][d]*Wout[i][h*64+d]
// ---------------------------------------------------------------------------
__global__ __launch_bounds__(256)
void attn_kernel(const float* __restrict__ stp, const float* __restrict__ normp,
                 const float* __restrict__ Wq, const float* __restrict__ Wk,
                 const float* __restrict__ Wv, const float* __restrict__ Wout,
                 float* __restrict__ Mt) {
    __shared__ float st[64][68];
    __shared__ float ql[64][68];
    __shared__ float kl[64][68];
    __shared__ float vl[64][68];
    __shared__ float sc[64][68];
    __shared__ float nrm[64];
    const int h = blockIdx.x;
    const int t = threadIdx.x;

    for (int e = t; e < 4096; e += 256) {
        float s = 0.f;
        for (int ch = 0; ch < 64; ++ch) s += stp[(((size_t)h*64) + ch)*4096 + e];
        st[e>>6][e&63] = s;
    }
    if (t < 64) {
        float s = 0.f;
        for (int ch = 0; ch < 64; ++ch) s += normp[(((size_t)h*64) + ch)*64 + t];
        nrm[t] = s + 1e-5f;
    }
    __syncthreads();
    for (int e = t; e < 4096; e += 256) st[e>>6][e&63] /= nrm[e>>6];
    __syncthreads();
    for (int e = t; e < 4096; e += 256) {
        int g = e >> 6, dd = e & 63;
        float aq = 0.f, ak = 0.f, av = 0.f;
        for (int cc = 0; cc < 64; ++cc) {
            float sv = st[g][cc];
            aq = fmaf(sv, Wq[dd*64 + cc], aq);
            ak = fmaf(sv, Wk[dd*64 + cc], ak);
            av = fmaf(sv, Wv[dd*64 + cc], av);
        }
        ql[g][dd] = aq; kl[g][dd] = ak; vl[g][dd] = av;
    }
    __syncthreads();
    for (int e = t; e < 4096; e += 256) {
        int g = e >> 6, gp = e & 63;
        float s = 0.f;
        for (int dd = 0; dd < 64; ++dd) s = fmaf(ql[g][dd], kl[gp][dd], s);
        sc[g][gp] = s * 0.125f;  // d^-0.5, d=64
    }
    __syncthreads();
    if (t < 64) {
        float m = -1e30f;
        for (int j = 0; j < 64; ++j) m = fmaxf(m, sc[t][j]);
        float ssum = 0.f;
        for (int j = 0; j < 64; ++j) { float p = expf(sc[t][j] - m); sc[t][j] = p; ssum += p; }
        float inv = 1.f / ssum;
        for (int j = 0; j < 64; ++j) sc[t][j] *= inv;
    }
    __syncthreads();
    for (int e = t; e < 4096; e += 256) {      // out_slice -> st (reuse)
        int g = e >> 6, dd = e & 63;
        float s = 0.f;
        for (int gp = 0; gp < 64; ++gp) s = fmaf(sc[g][gp], vl[gp][dd], s);
        st[g][dd] = s;
    }
    __syncthreads();
    for (int e = t; e < 16384; e += 256) {
        int i = e >> 6, g = e & 63;
        float s = 0.f;
        for (int dd = 0; dd < 64; ++dd)
            s = fmaf(st[g][dd], Wout[(size_t)i * HDIM + h*64 + dd], s);
        Mt[(size_t)i * HDIM + h*64 + g] = s;
    }
}

// ---------------------------------------------------------------------------
extern "C" void kernel_launch(void* const* d_in, const int* in_sizes, int n_in,
                              void* d_out, int out_size, void* d_ws, size_t ws_size,
                              hipStream_t stream) {
    const float* x    = (const float*)d_in[0];
    const float* Wx   = (const float*)d_in[1];
    const float* bx   = (const float*)d_in[2];
    const float* Wt1  = (const float*)d_in[3];
    const float* bt1  = (const float*)d_in[4];
    const float* Wt2  = (const float*)d_in[5];
    const float* bt2  = (const float*)d_in[6];
    const float* biasp= (const float*)d_in[7];
    const float* Ws   = (const float*)d_in[8];
    const float* bs   = (const float*)d_in[9];
    const float* Wq   = (const float*)d_in[10];
    const float* Wk   = (const float*)d_in[11];
    const float* Wv   = (const float*)d_in[12];
    const float* Wout = (const float*)d_in[13];
    const float* bout = (const float*)d_in[14];
    const float* u    = (const float*)d_in[15];
    float* out = (float*)d_out;

    float* ws    = (float*)d_ws;
    float* xmid  = ws;                                   // 65536*512
    float* sw    = xmid  + (size_t)NPTS * HDIM;          // 65536*512
    float* stp   = sw    + (size_t)NPTS * HDIM;          // 8*64*4096
    float* normp = stp   + (size_t)NH * 64 * 4096;       // 8*64*64
    float* Mt    = normp + (size_t)NH * 64 * 64;         // 256*512

    // 1) x_mid = x @ Wx^T + bx
    gemm_f32<256><<<dim3(512, 4), 256, 0, stream>>>(x, Wx, bx, xmid, 512);
    // 2) slice weights (temp MLP + logits + gumbel softmax)
    slice_weights_kernel<<<2048, 256, 0, stream>>>(xmid, Wt1, bt1, Wt2, bt2,
                                                   biasp, Ws, bs, u, sw);
    // 3) slice token partials
    gather_kernel<<<dim3(64, 8), 256, 0, stream>>>(xmid, sw, stp, normp);
    // 4) tiny attention + fold Wout
    attn_kernel<<<8, 256, 0, stream>>>(stp, normp, Wq, Wk, Wv, Wout, Mt);
    // 5) out = sw_flat @ Mt^T + bout
    gemm_f32<512><<<dim3(512, 2), 256, 0, stream>>>(sw, Mt, bout, out, 256);
}